// Round 1
// baseline (1567.315 us; speedup 1.0000x reference)
//
#include <hip/hip_runtime.h>

typedef __bf16 bf16x8 __attribute__((ext_vector_type(8)));
typedef float  f32x4  __attribute__((ext_vector_type(4)));

constexpr int M_ROWS = 65536;
constexpr int N_COLS = 2048;
constexpr int K_DIM  = 512;
constexpr int BM = 128, BN = 128, BK = 32;
constexpr int LDSK = 40;               // padded bf16 row stride (elems): balanced banks
constexpr int SEC  = 128 * LDSK;       // 5120 ushorts per LDS section
constexpr int NKT  = K_DIM / BK;       // 16 K-steps

constexpr size_t A_ELEMS = (size_t)M_ROWS * K_DIM;   // 33554432
constexpr size_t W_ELEMS = (size_t)N_COLS * K_DIM;   // 1048576

__device__ __forceinline__ unsigned short f2bf(float f){
  unsigned int u = __float_as_uint(f);
  u += 0x7FFFu + ((u >> 16) & 1u);     // RNE
  return (unsigned short)(u >> 16);
}
__device__ __forceinline__ float bf2f(unsigned short h){
  return __uint_as_float(((unsigned int)h) << 16);
}
__device__ __forceinline__ void split4(const float4& v, ushort4& h, ushort4& l){
  h.x = f2bf(v.x); l.x = f2bf(v.x - bf2f(h.x));
  h.y = f2bf(v.y); l.y = f2bf(v.y - bf2f(h.y));
  h.z = f2bf(v.z); l.z = f2bf(v.z - bf2f(h.z));
  h.w = f2bf(v.w); l.w = f2bf(v.w - bf2f(h.w));
}

// ---- prepass: X (f32 row-major [m][k]) -> Ahi/Alo bf16 row-major ----
__global__ void split_x_kernel(const float* __restrict__ X,
                               unsigned short* __restrict__ hi,
                               unsigned short* __restrict__ lo){
  const int n4 = (int)(A_ELEMS / 4);
  ushort4* h4 = reinterpret_cast<ushort4*>(hi);
  ushort4* l4 = reinterpret_cast<ushort4*>(lo);
  const float4* x4 = reinterpret_cast<const float4*>(X);
  for (int i = blockIdx.x * blockDim.x + threadIdx.x; i < n4; i += gridDim.x * blockDim.x){
    float4 v = x4[i];
    ushort4 h, l;
    split4(v, h, l);
    h4[i] = h; l4[i] = l;
  }
}

// ---- prepass: W (f32 [k][n]) -> Wt_hi/Wt_lo bf16 [n][k] (transpose+split) ----
__global__ void split_w_kernel(const float* __restrict__ W,
                               unsigned short* __restrict__ hi,
                               unsigned short* __restrict__ lo){
  __shared__ float t[32][33];
  int n0 = blockIdx.x * 32, k0 = blockIdx.y * 32;
  int tx = threadIdx.x & 31, ty = threadIdx.x >> 5;
  #pragma unroll
  for (int r = 0; r < 4; ++r)
    t[ty + r*8][tx] = W[(size_t)(k0 + ty + r*8) * N_COLS + n0 + tx];
  __syncthreads();
  #pragma unroll
  for (int r = 0; r < 4; ++r){
    int nl = ty + r*8;
    float v = t[tx][nl];                     // W[k0+tx][n0+nl]
    unsigned short h = f2bf(v);
    unsigned short l = f2bf(v - bf2f(h));
    size_t o = (size_t)(n0 + nl) * K_DIM + k0 + tx;
    hi[o] = h; lo[o] = l;
  }
}

// ---- main GEMM + cos epilogue ----
// MODE 0: A and W pre-split in ws.  MODE 1: only W pre-split.  MODE 2: no ws.
template<int MODE>
__launch_bounds__(256, 2)
__global__ void rbf_gemm(const float* __restrict__ X, const float* __restrict__ W,
                         const float* __restrict__ bvec,
                         const unsigned short* __restrict__ wsbase, // = Ahi (mode0) / Whi (mode1)
                         float* __restrict__ out){
  __shared__ __align__(16) unsigned short smem[4 * SEC];  // Ahi|Alo|Bhi|Blo, padded rows

  // bijective XCD swizzle: gridDim.x = 8192, 8192 % 8 == 0
  int orig = blockIdx.x;
  int wgid = (orig & 7) * (int)(gridDim.x >> 3) + (orig >> 3);
  int mb = wgid >> 4, nb = wgid & 15;
  int m0 = mb * BM, n0 = nb * BN;

  int tid  = threadIdx.x;
  int lane = tid & 63, wid = tid >> 6;
  int wm = wid >> 1, wn = wid & 1;
  int r = lane & 15, g = lane >> 4;

  // -------- staging state (per-mode; unused ones are DCE'd) --------
  int    gofs16[8]; int lofs16[8]; int4 rg16[8];         // mode 0
  const float* asrc[4]; int alofs[4]; float4 ra[4];      // modes 1,2 (A from f32)
  const unsigned short* bsrc[4]; int blofs[4]; int4 rb[4]; // mode 1
  const float* wsrc[4]; int wnq4[4]; int wkr[4]; float4 rw[4]; // mode 2

  if constexpr (MODE == 0){
    #pragma unroll
    for (int i = 0; i < 8; ++i){
      int c = tid + i * 256;                 // 2048 16B-chunks per K-step
      int sec = c >> 9, row = (c >> 2) & 127, q = c & 3;
      size_t secoff = (sec == 0) ? 0 : (sec == 1) ? A_ELEMS
                    : (sec == 2) ? 2*A_ELEMS : 2*A_ELEMS + W_ELEMS;
      int grow = ((sec < 2) ? m0 : n0) + row;
      gofs16[i] = (int)(secoff + (size_t)grow * K_DIM + q * 8);
      lofs16[i] = sec * SEC + row * LDSK + q * 8;
    }
    #pragma unroll
    for (int i = 0; i < 8; ++i)
      rg16[i] = *reinterpret_cast<const int4*>(wsbase + gofs16[i]);
  } else {
    #pragma unroll
    for (int i = 0; i < 4; ++i){
      int c = tid + i * 256;                 // 1024 float4 chunks of A
      int row = c >> 3, q = c & 7;
      asrc[i]  = X + (size_t)(m0 + row) * K_DIM + q * 4;
      alofs[i] = row * LDSK + q * 4;
    }
    #pragma unroll
    for (int i = 0; i < 4; ++i) ra[i] = *reinterpret_cast<const float4*>(asrc[i]);
    if constexpr (MODE == 1){
      #pragma unroll
      for (int i = 0; i < 4; ++i){
        int c = tid + i * 256;               // 1024 16B-chunks of Bhi/Blo
        int sec = c >> 9, row = (c >> 2) & 127, q = c & 3;
        bsrc[i]  = wsbase + (size_t)sec * W_ELEMS + (size_t)(n0 + row) * K_DIM + q * 8;
        blofs[i] = (2 + sec) * SEC + row * LDSK + q * 8;
      }
      #pragma unroll
      for (int i = 0; i < 4; ++i) rb[i] = *reinterpret_cast<const int4*>(bsrc[i]);
    } else {
      #pragma unroll
      for (int i = 0; i < 4; ++i){
        int c = tid + i * 256;               // 1024 float4 chunks of W tile [32k][128n]
        int kr = c >> 5, nq = c & 31;
        wsrc[i] = W + (size_t)kr * N_COLS + n0 + nq * 4;
        wkr[i] = kr; wnq4[i] = nq * 4;
      }
      #pragma unroll
      for (int i = 0; i < 4; ++i) rw[i] = *reinterpret_cast<const float4*>(wsrc[i]);
    }
  }

  f32x4 acc[4][4];
  f32x4 zero = {0.f, 0.f, 0.f, 0.f};
  #pragma unroll
  for (int i = 0; i < 4; ++i)
    #pragma unroll
    for (int j = 0; j < 4; ++j) acc[i][j] = zero;

  int aoff[4], boff[4];
  #pragma unroll
  for (int i = 0; i < 4; ++i) aoff[i] = (wm*64 + i*16 + r) * LDSK + g * 8;
  #pragma unroll
  for (int j = 0; j < 4; ++j) boff[j] = (wn*64 + j*16 + r) * LDSK + g * 8;

  #pragma unroll 1
  for (int kt = 0; kt < NKT; ++kt){
    __syncthreads();                          // previous compute done reading LDS
    // ---- write staged regs -> LDS ----
    if constexpr (MODE == 0){
      #pragma unroll
      for (int i = 0; i < 8; ++i)
        *reinterpret_cast<int4*>(&smem[lofs16[i]]) = rg16[i];
    } else {
      #pragma unroll
      for (int i = 0; i < 4; ++i){
        ushort4 h, l;
        split4(ra[i], h, l);
        *reinterpret_cast<ushort4*>(&smem[alofs[i]])        = h;
        *reinterpret_cast<ushort4*>(&smem[SEC + alofs[i]])  = l;
      }
      if constexpr (MODE == 1){
        #pragma unroll
        for (int i = 0; i < 4; ++i)
          *reinterpret_cast<int4*>(&smem[blofs[i]]) = rb[i];
      } else {
        #pragma unroll
        for (int i = 0; i < 4; ++i){
          float vv[4] = {rw[i].x, rw[i].y, rw[i].z, rw[i].w};
          #pragma unroll
          for (int w2 = 0; w2 < 4; ++w2){
            unsigned short h = f2bf(vv[w2]);
            unsigned short l = f2bf(vv[w2] - bf2f(h));
            int n = wnq4[i] + w2;
            smem[2*SEC + n*LDSK + wkr[i]] = h;
            smem[3*SEC + n*LDSK + wkr[i]] = l;
          }
        }
      }
    }
    // ---- prefetch next K-step into regs (hides HBM under compute) ----
    if (kt < NKT - 1){
      if constexpr (MODE == 0){
        #pragma unroll
        for (int i = 0; i < 8; ++i)
          rg16[i] = *reinterpret_cast<const int4*>(wsbase + gofs16[i] + (kt+1)*BK);
      } else {
        #pragma unroll
        for (int i = 0; i < 4; ++i)
          ra[i] = *reinterpret_cast<const float4*>(asrc[i] + (kt+1)*BK);
        if constexpr (MODE == 1){
          #pragma unroll
          for (int i = 0; i < 4; ++i)
            rb[i] = *reinterpret_cast<const int4*>(bsrc[i] + (kt+1)*BK);
        } else {
          #pragma unroll
          for (int i = 0; i < 4; ++i)
            rw[i] = *reinterpret_cast<const float4*>(wsrc[i] + (size_t)(kt+1)*BK*N_COLS);
        }
      }
    }
    __syncthreads();                          // LDS tile ready
    // ---- compute: 16 ds_read_b128 + 48 MFMA per wave ----
    bf16x8 ah[4], al[4], bh[4], bl[4];
    #pragma unroll
    for (int i = 0; i < 4; ++i){
      ah[i] = *reinterpret_cast<const bf16x8*>(&smem[aoff[i]]);
      al[i] = *reinterpret_cast<const bf16x8*>(&smem[SEC + aoff[i]]);
    }
    #pragma unroll
    for (int j = 0; j < 4; ++j){
      bh[j] = *reinterpret_cast<const bf16x8*>(&smem[2*SEC + boff[j]]);
      bl[j] = *reinterpret_cast<const bf16x8*>(&smem[3*SEC + boff[j]]);
    }
    #pragma unroll
    for (int i = 0; i < 4; ++i){
      #pragma unroll
      for (int j = 0; j < 4; ++j){
        acc[i][j] = __builtin_amdgcn_mfma_f32_16x16x32_bf16(ah[i], bh[j], acc[i][j], 0, 0, 0);
        acc[i][j] = __builtin_amdgcn_mfma_f32_16x16x32_bf16(al[i], bh[j], acc[i][j], 0, 0, 0);
        acc[i][j] = __builtin_amdgcn_mfma_f32_16x16x32_bf16(ah[i], bl[j], acc[i][j], 0, 0, 0);
      }
    }
  }

  // ---- epilogue: +b, cos, *sqrt(2/2048)=1/32 ----
  float bv[4];
  #pragma unroll
  for (int j = 0; j < 4; ++j) bv[j] = bvec[n0 + wn*64 + j*16 + r];
  constexpr float INV2PI = 0.15915494309189535f;
  #pragma unroll
  for (int i = 0; i < 4; ++i){
    #pragma unroll
    for (int j = 0; j < 4; ++j){
      int col = n0 + wn*64 + j*16 + r;
      #pragma unroll
      for (int p = 0; p < 4; ++p){
        int row = m0 + wm*64 + i*16 + g*4 + p;
        float v = acc[i][j][p] + bv[j];
        float rev = v * INV2PI;               // radians -> revolutions
        rev -= floorf(rev);                   // [0,1) for v_cos HW range
        out[(size_t)row * N_COLS + col] = 0.03125f * __builtin_amdgcn_cosf(rev);
      }
    }
  }
}

extern "C" void kernel_launch(void* const* d_in, const int* in_sizes, int n_in,
                              void* d_out, int out_size, void* d_ws, size_t ws_size,
                              hipStream_t stream){
  const float* X = (const float*)d_in[0];
  const float* W = (const float*)d_in[1];
  const float* b = (const float*)d_in[2];
  float* out = (float*)d_out;
  unsigned short* ws = (unsigned short*)d_ws;

  const size_t needA = 2 * A_ELEMS * sizeof(unsigned short);  // 128 MiB
  const size_t needW = 2 * W_ELEMS * sizeof(unsigned short);  // 4 MiB

  dim3 grid(8192), block(256);
  if (ws && ws_size >= needA + needW){
    unsigned short* Ahi = ws;
    unsigned short* Whi = ws + 2 * A_ELEMS;
    unsigned short* Wlo = Whi + W_ELEMS;
    split_x_kernel<<<2048, 256, 0, stream>>>(X, Ahi, Ahi + A_ELEMS);
    split_w_kernel<<<dim3(64, 16), 256, 0, stream>>>(W, Whi, Wlo);
    rbf_gemm<0><<<grid, block, 0, stream>>>(X, W, b, Ahi, out);
  } else if (ws && ws_size >= needW){
    unsigned short* Whi = ws;
    split_w_kernel<<<dim3(64, 16), 256, 0, stream>>>(W, Whi, Whi + W_ELEMS);
    rbf_gemm<1><<<grid, block, 0, stream>>>(X, W, b, Whi, out);
  } else {
    rbf_gemm<2><<<grid, block, 0, stream>>>(X, W, b, nullptr, out);
  }
}

// Round 2
// 415.238 us; speedup vs baseline: 3.7745x; 3.7745x over previous
//
#include <hip/hip_runtime.h>

typedef __bf16 bf16x8 __attribute__((ext_vector_type(8)));
typedef float  f32x4  __attribute__((ext_vector_type(4)));

constexpr int M_ROWS = 65536;
constexpr int N_COLS = 2048;
constexpr int K_DIM  = 512;
constexpr int BM = 128, BN = 128, BK = 32;
constexpr int NKT = K_DIM / BK;        // 16 K-steps
constexpr int MB_CNT = M_ROWS / BM;    // 512
constexpr int NB_CNT = N_COLS / BN;    // 16

constexpr size_t A_ELEMS = (size_t)M_ROWS * K_DIM;
constexpr size_t W_ELEMS = (size_t)N_COLS * K_DIM;
// packed blocks: per (tile, kt): [hi 4096 ushorts][lo 4096 ushorts] = 16 KB
constexpr size_t APK_USHORTS = (size_t)MB_CNT * NKT * 8192;  // 67,108,864 (128 MiB)
constexpr size_t WPK_USHORTS = (size_t)NB_CNT * NKT * 8192;  //  2,097,152 (4 MiB)

__device__ __forceinline__ unsigned short f2bf(float f){
  unsigned int u = __float_as_uint(f);
  u += 0x7FFFu + ((u >> 16) & 1u);     // RNE
  return (unsigned short)(u >> 16);
}
__device__ __forceinline__ float bf2f(unsigned short h){
  return __uint_as_float(((unsigned int)h) << 16);
}
__device__ __forceinline__ void split4(const float4& v, ushort4& h, ushort4& l){
  h.x = f2bf(v.x); l.x = f2bf(v.x - bf2f(h.x));
  h.y = f2bf(v.y); l.y = f2bf(v.y - bf2f(h.y));
  h.z = f2bf(v.z); l.z = f2bf(v.z - bf2f(h.z));
  h.w = f2bf(v.w); l.w = f2bf(v.w - bf2f(h.w));
}

__device__ __forceinline__ void gl_lds16(const void* g, void* l){
  __builtin_amdgcn_global_load_lds(
      (const __attribute__((address_space(1))) unsigned int*)g,
      (__attribute__((address_space(3))) unsigned int*)l, 16, 0, 0);
}

constexpr float INV2PI = 0.15915494309189535f;
__device__ __forceinline__ float cos_scaled(float v){
  float rev = v * INV2PI;
  rev -= floorf(rev);                   // [0,1) revolutions for v_cos
  return 0.03125f * __builtin_amdgcn_cosf(rev);
}

// ---------------- prepass: X -> Apk (fragment-linear, hi/lo split) ----------
// Apk block (mb,kt): chunk c = i*64 + q*16 + r  <->  A row mb*128+i*16+r,
// k = kt*32 + q*8 .. +7 (bf16, k-contiguous). hi at +0, lo at +4096 ushorts.
__global__ void pack_x(const float* __restrict__ X, unsigned short* __restrict__ Apk){
  __shared__ __align__(16) unsigned short lds[8192];
  const int mb = blockIdx.x, kt = blockIdx.y, t = threadIdx.x;
  const float* src = X + (size_t)mb * 128 * K_DIM + kt * 32;
  const int fq = t & 7, r0 = t >> 3;
  #pragma unroll
  for (int it = 0; it < 4; ++it){
    int row = r0 + it * 32;
    float4 v = *reinterpret_cast<const float4*>(src + (size_t)row * K_DIM + fq * 4);
    ushort4 h, l; split4(v, h, l);
    int i = row >> 4, r = row & 15, q = fq >> 1, half = fq & 1;
    int base = (i * 64 + q * 16 + r) * 8 + half * 4;
    *reinterpret_cast<ushort4*>(lds + base)        = h;
    *reinterpret_cast<ushort4*>(lds + 4096 + base) = l;
  }
  __syncthreads();
  unsigned short* dst = Apk + ((size_t)mb * NKT + kt) * 8192;
  #pragma unroll
  for (int it = 0; it < 4; ++it){
    int c = t + it * 256;
    *reinterpret_cast<int4*>(dst + c * 8) = *reinterpret_cast<const int4*>(lds + c * 8);
  }
}

// ---------------- prepass: W -> Wpk (transpose + fragment-linear + col-perm) -
// Wpk block (nb,kt): chunk c = s*64 + q*16 + fc holds W[k=kt*32+q*8..][n],
// n = nb*128 + (s>>2)*64 + fc*4 + (s&3)  -- column permutation so the
// epilogue writes contiguous float4 per lane.
__global__ void pack_w(const float* __restrict__ W, unsigned short* __restrict__ Wpk){
  __shared__ __align__(16) unsigned short lds[8192];
  const int nb = blockIdx.x, kt = blockIdx.y, t = threadIdx.x;
  const int nq = t & 31, kr0 = t >> 5;
  #pragma unroll
  for (int it = 0; it < 4; ++it){
    int kr = kr0 + it * 8;
    float4 v = *reinterpret_cast<const float4*>(
        W + (size_t)(kt * 32 + kr) * N_COLS + nb * 128 + nq * 4);
    float vv[4] = {v.x, v.y, v.z, v.w};
    int q = kr >> 3, ko = kr & 7;
    #pragma unroll
    for (int c = 0; c < 4; ++c){
      int nl = nq * 4 + c;
      int s  = ((nl >> 6) << 2) + (nl & 3);
      int fc = (nl >> 2) & 15;
      unsigned short h = f2bf(vv[c]);
      unsigned short l = f2bf(vv[c] - bf2f(h));
      int e = (s * 64 + q * 16 + fc) * 8 + ko;
      lds[e] = h; lds[4096 + e] = l;
    }
  }
  __syncthreads();
  unsigned short* dst = Wpk + ((size_t)nb * NKT + kt) * 8192;
  #pragma unroll
  for (int it = 0; it < 4; ++it){
    int c = t + it * 256;
    *reinterpret_cast<int4*>(dst + c * 8) = *reinterpret_cast<const int4*>(lds + c * 8);
  }
}

// ---------------- main GEMM + cos epilogue (packed path) --------------------
__launch_bounds__(256, 2)
__global__ void rbf_gemm_pk(const unsigned short* __restrict__ Apk,
                            const unsigned short* __restrict__ Wpk,
                            const float* __restrict__ bvec,
                            float* __restrict__ out){
  // LDS image per K-step: [A hi 8K][A lo 8K][B hi 8K][B lo 8K] bytes,
  // each 8K = 8 subtiles x (64 lanes x 16 B fragment-linear)
  __shared__ __align__(16) unsigned short smem[16384];

  int orig = blockIdx.x;                       // 8192 blocks, 8192 % 8 == 0
  int wgid = (orig & 7) * 1024 + (orig >> 3);  // bijective XCD swizzle
  int mb = wgid >> 4, nb = wgid & 15;
  int m0 = mb * BM, n0 = nb * BN;

  int tid = threadIdx.x, lane = tid & 63, wid = tid >> 6;
  int wm = wid >> 1, wn = wid & 1;
  int r = lane & 15, g = lane >> 4;

  const char* asrc = (const char*)(Apk + (size_t)mb * NKT * 8192);
  const char* bsrc = (const char*)(Wpk + (size_t)nb * NKT * 8192);
  char* ldsb = (char*)smem;

  f32x4 acc[4][4];
  f32x4 zero = {0.f, 0.f, 0.f, 0.f};
  #pragma unroll
  for (int i = 0; i < 4; ++i)
    #pragma unroll
    for (int j = 0; j < 4; ++j) acc[i][j] = zero;

  const int lbase = lane * 8;                  // ushort offset of this lane's chunk

  #pragma unroll 1
  for (int kt = 0; kt < NKT; ++kt){
    __syncthreads();                           // all waves done reading prev tile
    const char* ab = asrc + (size_t)kt * 16384 + tid * 16;
    const char* bb = bsrc + (size_t)kt * 16384 + tid * 16;
    #pragma unroll
    for (int it = 0; it < 4; ++it)
      gl_lds16(ab + it * 4096, ldsb + it * 4096 + wid * 1024);
    #pragma unroll
    for (int it = 0; it < 4; ++it)
      gl_lds16(bb + it * 4096, ldsb + 16384 + it * 4096 + wid * 1024);
    __syncthreads();                           // vmcnt(0) drain + barrier: tile ready

    bf16x8 ah[4], al[4], bh[4], bl[4];
    #pragma unroll
    for (int i = 0; i < 4; ++i){
      int o = (wm * 4 + i) * 512 + lbase;
      ah[i] = *reinterpret_cast<const bf16x8*>(&smem[o]);
      al[i] = *reinterpret_cast<const bf16x8*>(&smem[o + 4096]);
    }
    #pragma unroll
    for (int j = 0; j < 4; ++j){
      int o = 8192 + (wn * 4 + j) * 512 + lbase;
      bh[j] = *reinterpret_cast<const bf16x8*>(&smem[o]);
      bl[j] = *reinterpret_cast<const bf16x8*>(&smem[o + 4096]);
    }
    #pragma unroll
    for (int i = 0; i < 4; ++i){
      #pragma unroll
      for (int j = 0; j < 4; ++j){
        acc[i][j] = __builtin_amdgcn_mfma_f32_16x16x32_bf16(ah[i], bh[j], acc[i][j], 0, 0, 0);
        acc[i][j] = __builtin_amdgcn_mfma_f32_16x16x32_bf16(al[i], bh[j], acc[i][j], 0, 0, 0);
        acc[i][j] = __builtin_amdgcn_mfma_f32_16x16x32_bf16(ah[i], bl[j], acc[i][j], 0, 0, 0);
      }
    }
  }

  // epilogue: col for acc[i][j] lane(r,g) reg p = n0 + wn*64 + r*4 + j
  //           row = m0 + wm*64 + i*16 + g*4 + p  -> float4 stores, full lines
  int colb = n0 + wn * 64 + r * 4;
  float4 bv = *reinterpret_cast<const float4*>(bvec + colb);
  #pragma unroll
  for (int i = 0; i < 4; ++i){
    #pragma unroll
    for (int p = 0; p < 4; ++p){
      int row = m0 + wm * 64 + i * 16 + g * 4 + p;
      float4 o;
      o.x = cos_scaled(acc[i][0][p] + bv.x);
      o.y = cos_scaled(acc[i][1][p] + bv.y);
      o.z = cos_scaled(acc[i][2][p] + bv.z);
      o.w = cos_scaled(acc[i][3][p] + bv.w);
      *reinterpret_cast<float4*>(out + (size_t)row * N_COLS + colb) = o;
    }
  }
}

// ---------------- fallback (no workspace): round-1 mode-2 kernel ------------
constexpr int LDSK = 40;
constexpr int SEC  = 128 * LDSK;
__launch_bounds__(256, 2)
__global__ void rbf_gemm_nows(const float* __restrict__ X, const float* __restrict__ W,
                              const float* __restrict__ bvec, float* __restrict__ out){
  __shared__ __align__(16) unsigned short smem[4 * SEC];
  int orig = blockIdx.x;
  int wgid = (orig & 7) * (int)(gridDim.x >> 3) + (orig >> 3);
  int mb = wgid >> 4, nb = wgid & 15;
  int m0 = mb * BM, n0 = nb * BN;
  int tid = threadIdx.x, lane = tid & 63, wid = tid >> 6;
  int wm = wid >> 1, wn = wid & 1;
  int r = lane & 15, g = lane >> 4;

  const float* asrc[4]; int alofs[4]; float4 ra[4];
  const float* wsrc[4]; int wnq4[4]; int wkr[4]; float4 rw[4];
  #pragma unroll
  for (int i = 0; i < 4; ++i){
    int c = tid + i * 256;
    int row = c >> 3, q = c & 7;
    asrc[i]  = X + (size_t)(m0 + row) * K_DIM + q * 4;
    alofs[i] = row * LDSK + q * 4;
  }
  #pragma unroll
  for (int i = 0; i < 4; ++i) ra[i] = *reinterpret_cast<const float4*>(asrc[i]);
  #pragma unroll
  for (int i = 0; i < 4; ++i){
    int c = tid + i * 256;
    int kr = c >> 5, nq = c & 31;
    wsrc[i] = W + (size_t)kr * N_COLS + n0 + nq * 4;
    wkr[i] = kr; wnq4[i] = nq * 4;
  }
  #pragma unroll
  for (int i = 0; i < 4; ++i) rw[i] = *reinterpret_cast<const float4*>(wsrc[i]);

  f32x4 acc[4][4];
  f32x4 zero = {0.f, 0.f, 0.f, 0.f};
  #pragma unroll
  for (int i = 0; i < 4; ++i)
    #pragma unroll
    for (int j = 0; j < 4; ++j) acc[i][j] = zero;

  int aoff[4], boff[4];
  #pragma unroll
  for (int i = 0; i < 4; ++i) aoff[i] = (wm*64 + i*16 + r) * LDSK + g * 8;
  #pragma unroll
  for (int j = 0; j < 4; ++j) boff[j] = (wn*64 + j*16 + r) * LDSK + g * 8;

  #pragma unroll 1
  for (int kt = 0; kt < NKT; ++kt){
    __syncthreads();
    #pragma unroll
    for (int i = 0; i < 4; ++i){
      ushort4 h, l;
      split4(ra[i], h, l);
      *reinterpret_cast<ushort4*>(&smem[alofs[i]])       = h;
      *reinterpret_cast<ushort4*>(&smem[SEC + alofs[i]]) = l;
    }
    #pragma unroll
    for (int i = 0; i < 4; ++i){
      float vv[4] = {rw[i].x, rw[i].y, rw[i].z, rw[i].w};
      #pragma unroll
      for (int w2 = 0; w2 < 4; ++w2){
        unsigned short h = f2bf(vv[w2]);
        unsigned short l = f2bf(vv[w2] - bf2f(h));
        int n = wnq4[i] + w2;
        smem[2*SEC + n*LDSK + wkr[i]] = h;
        smem[3*SEC + n*LDSK + wkr[i]] = l;
      }
    }
    if (kt < NKT - 1){
      #pragma unroll
      for (int i = 0; i < 4; ++i)
        ra[i] = *reinterpret_cast<const float4*>(asrc[i] + (kt+1)*BK);
      #pragma unroll
      for (int i = 0; i < 4; ++i)
        rw[i] = *reinterpret_cast<const float4*>(wsrc[i] + (size_t)(kt+1)*BK*N_COLS);
    }
    __syncthreads();
    bf16x8 ah[4], al[4], bh[4], bl[4];
    #pragma unroll
    for (int i = 0; i < 4; ++i){
      ah[i] = *reinterpret_cast<const bf16x8*>(&smem[aoff[i]]);
      al[i] = *reinterpret_cast<const bf16x8*>(&smem[SEC + aoff[i]]);
    }
    #pragma unroll
    for (int j = 0; j < 4; ++j){
      bh[j] = *reinterpret_cast<const bf16x8*>(&smem[2*SEC + boff[j]]);
      bl[j] = *reinterpret_cast<const bf16x8*>(&smem[3*SEC + boff[j]]);
    }
    #pragma unroll
    for (int i = 0; i < 4; ++i){
      #pragma unroll
      for (int j = 0; j < 4; ++j){
        acc[i][j] = __builtin_amdgcn_mfma_f32_16x16x32_bf16(ah[i], bh[j], acc[i][j], 0, 0, 0);
        acc[i][j] = __builtin_amdgcn_mfma_f32_16x16x32_bf16(al[i], bh[j], acc[i][j], 0, 0, 0);
        acc[i][j] = __builtin_amdgcn_mfma_f32_16x16x32_bf16(ah[i], bl[j], acc[i][j], 0, 0, 0);
      }
    }
  }

  float bvv[4];
  #pragma unroll
  for (int j = 0; j < 4; ++j) bvv[j] = bvec[n0 + wn*64 + j*16 + r];
  #pragma unroll
  for (int i = 0; i < 4; ++i){
    #pragma unroll
    for (int j = 0; j < 4; ++j){
      int col = n0 + wn*64 + j*16 + r;
      #pragma unroll
      for (int p = 0; p < 4; ++p){
        int row = m0 + wm*64 + i*16 + g*4 + p;
        out[(size_t)row * N_COLS + col] = cos_scaled(acc[i][j][p] + bvv[j]);
      }
    }
  }
}

extern "C" void kernel_launch(void* const* d_in, const int* in_sizes, int n_in,
                              void* d_out, int out_size, void* d_ws, size_t ws_size,
                              hipStream_t stream){
  const float* X = (const float*)d_in[0];
  const float* W = (const float*)d_in[1];
  const float* b = (const float*)d_in[2];
  float* out = (float*)d_out;
  unsigned short* ws = (unsigned short*)d_ws;

  const size_t needP = (APK_USHORTS + WPK_USHORTS) * sizeof(unsigned short); // 132 MiB

  if (ws && ws_size >= needP){
    unsigned short* Apk = ws;
    unsigned short* Wpk = ws + APK_USHORTS;
    pack_x<<<dim3(MB_CNT, NKT), 256, 0, stream>>>(X, Apk);
    pack_w<<<dim3(NB_CNT, NKT), 256, 0, stream>>>(W, Wpk);
    rbf_gemm_pk<<<8192, 256, 0, stream>>>(Apk, Wpk, b, out);
  } else {
    rbf_gemm_nows<<<8192, 256, 0, stream>>>(X, W, b, out);
  }
}